// Round 4
// baseline (347.653 us; speedup 1.0000x reference)
//
#include <hip/hip_runtime.h>
#include <stdint.h>

#define BTOT 32768
#define NIMG 16      // images per conv block
#define KF   416     // padded feature dim (400 real)

typedef __attribute__((ext_vector_type(2))) _Float16 half2r;
typedef __attribute__((ext_vector_type(8))) short short8;
typedef __attribute__((ext_vector_type(4))) float floatx4;

static __device__ __forceinline__ half2r u2h(unsigned int u) {
    return __builtin_bit_cast(half2r, u);
}
static __device__ __forceinline__ unsigned int h2u(half2r h) {
    return __builtin_bit_cast(unsigned int, h);
}
static __device__ __forceinline__ half2r cvt2h(float a, float b) {
    return __builtin_bit_cast(half2r, __builtin_amdgcn_cvt_pkrtz(a, b));
}
__device__ __forceinline__ unsigned short f2bf(float x) {
    union { float f; unsigned int u; } v; v.f = x;
    unsigned int r = v.u + 0x7fffu + ((v.u >> 16) & 1u);  // RNE
    return (unsigned short)(r >> 16);
}

// ---------------- conv(5x5,3->16) + bias + relu + 2x2 maxpool -> bf16 features ----------------
// (unchanged from round 3 — met prediction, est. ~60 us)
__global__ __launch_bounds__(256) void conv_pool_kernel(
    const float* __restrict__ fm, const float* __restrict__ cw,
    const float* __restrict__ cb, unsigned short* __restrict__ feat)
{
    __shared__ __align__(16) unsigned int s_img[NIMG * 294];
    __shared__ unsigned int s_w2[16 * 76];

    const int tid = threadIdx.x;
    const int b0 = blockIdx.x * NIMG;

    const float4* in4 = (const float4*)fm;
    for (int idx = tid; idx < NIMG * 147; idx += 256) {
        float4 v = in4[(size_t)b0 * 147 + idx];
        half2r lo = cvt2h(v.x, v.y);
        half2r hi = cvt2h(v.z, v.w);
        *(uint2*)&s_img[idx * 2] = make_uint2(h2u(lo), h2u(hi));
    }
    for (int idx = tid; idx < 1200; idx += 256) {
        int co = idx / 75;
        int r = idx - co * 75;
        float w = cw[idx];
        s_w2[co * 76 + r] = h2u(cvt2h(w, w));
    }
    __syncthreads();

    const int b_local = tid & 15;
    const int co = tid >> 4;
    const float bias = cb[co];
    const unsigned int* ibase = s_img + b_local * 294;
    const unsigned int* wbase = s_w2 + co * 76;
    unsigned short* fout = feat + (size_t)(b0 + b_local) * KF + co * 25;

    for (int r = 0; r < 5; ++r) {
        half2r acc0[5], acc1[5];
        #pragma unroll
        for (int p = 0; p < 5; ++p) { acc0[p] = u2h(0u); acc1[p] = u2h(0u); }

        #pragma unroll
        for (int ci = 0; ci < 3; ++ci) {
            const unsigned int* ip = ibase + ci * 98 + r * 14;
            unsigned int wr[25];
            #pragma unroll
            for (int k = 0; k < 25; ++k) wr[k] = wbase[ci * 25 + k];

            #pragma unroll
            for (int ir = 0; ir < 6; ++ir) {
                unsigned int v[7];
                #pragma unroll
                for (int q = 0; q < 7; ++q) v[q] = ip[ir * 7 + q];
                unsigned int s[6];
                #pragma unroll
                for (int q = 0; q < 6; ++q) s[q] = (v[q] >> 16) | (v[q + 1] << 16);

                if (ir < 5) {
                    #pragma unroll
                    for (int p = 0; p < 5; ++p) {
                        acc0[p] += u2h(v[p])     * u2h(wr[ir * 5 + 0]);
                        acc0[p] += u2h(s[p])     * u2h(wr[ir * 5 + 1]);
                        acc0[p] += u2h(v[p + 1]) * u2h(wr[ir * 5 + 2]);
                        acc0[p] += u2h(s[p + 1]) * u2h(wr[ir * 5 + 3]);
                        acc0[p] += u2h(v[p + 2]) * u2h(wr[ir * 5 + 4]);
                    }
                }
                if (ir >= 1) {
                    const int kh = ir - 1;
                    #pragma unroll
                    for (int p = 0; p < 5; ++p) {
                        acc1[p] += u2h(v[p])     * u2h(wr[kh * 5 + 0]);
                        acc1[p] += u2h(s[p])     * u2h(wr[kh * 5 + 1]);
                        acc1[p] += u2h(v[p + 1]) * u2h(wr[kh * 5 + 2]);
                        acc1[p] += u2h(s[p + 1]) * u2h(wr[kh * 5 + 3]);
                        acc1[p] += u2h(v[p + 2]) * u2h(wr[kh * 5 + 4]);
                    }
                }
            }
        }
        #pragma unroll
        for (int p = 0; p < 5; ++p) {
            float a = (float)acc0[p].x, b = (float)acc0[p].y;
            float c = (float)acc1[p].x, d = (float)acc1[p].y;
            float m = fmaxf(fmaxf(a, b), fmaxf(c, d)) + bias;
            m = fmaxf(m, 0.f);
            fout[r * 5 + p] = f2bf(m);
        }
    }
    if (co == 0) {
        uint4 z = make_uint4(0u, 0u, 0u, 0u);
        *(uint4*)(feat + (size_t)(b0 + b_local) * KF + 400) = z;
        *(uint4*)(feat + (size_t)(b0 + b_local) * KF + 408) = z;
    }
}

// ---------------- lin_w [1000][400] fp32 -> Wb [1024][416] bf16 (zero padded) ----------------
__global__ __launch_bounds__(256) void prep_w_kernel(const float* __restrict__ lw,
                                                     unsigned short* __restrict__ Wb)
{
    int c = blockIdx.x * 256 + threadIdx.x;
    if (c >= 1024 * 52) return;
    int n = c / 52;
    int kc = (c - n * 52) * 8;
    unsigned short v[8];
    #pragma unroll
    for (int j = 0; j < 8; ++j) {
        int k = kc + j;
        float x = (n < 1000 && k < 400) ? lw[n * 400 + k] : 0.f;
        v[j] = f2bf(x);
    }
    *(uint4*)(Wb + (size_t)n * KF + kc) = *(uint4*)v;
}

// ---------------- GEMM: out[32768][1000] = F[32768][416] @ Wb[1024][416]^T + lin_b ----------------
// B-resident structure: 128-n slab of W staged in LDS chunk-major ([c=k/8][n:128][8 halves],
// conflict-free b128 reads), in 2 K-halves (28+24 chunks, 57 KB). K-loop has NO barriers:
// A-fragments load direct global->VGPR (F is L3-resident), B-fragments from LDS.
// Wave tile 64m x 128n (acc 4x8 frags), block = 8 waves covering 512 m-rows.
#define H0C 28   // chunks (8 halves of k) in K-half 0: k 0..223
#define H1C 24   // K-half 1: k 224..415

__global__ __launch_bounds__(512, 2) void gemm_kernel(
    const unsigned short* __restrict__ F, const unsigned short* __restrict__ Wb,
    const float* __restrict__ lb, float* __restrict__ out)
{
    __shared__ __align__(16) unsigned short Bs[H0C * 128 * 8];  // 57344 B

    const int tid = threadIdx.x;
    const int lane = tid & 63;
    const int w = tid >> 6;           // 8 waves
    const int lq = lane >> 4, ln = lane & 15;

    const int slab = blockIdx.x & 7;          // n-slab (128 cols)
    const int mg = blockIdx.x >> 3;           // 64 m-groups of 512 rows
    const int n0 = slab * 128;
    const int mbase = mg * 512 + w * 64;      // wave's 64-row tile

    floatx4 zero = {0.f, 0.f, 0.f, 0.f};
    floatx4 acc[4][8];
    #pragma unroll
    for (int i = 0; i < 4; ++i)
        #pragma unroll
        for (int j = 0; j < 8; ++j) acc[i][j] = zero;

    const unsigned short* Arow = F + (size_t)(mbase + ln) * KF + lq * 8;

    #pragma unroll
    for (int half = 0; half < 2; ++half) {
        const int c0 = half ? H0C : 0;
        const int nch = half ? H1C : H0C;
        // stage B-slab half: chunk-major [c][n][8]
        for (int idx = tid; idx < nch * 128; idx += 512) {
            int c = idx >> 7;
            int n = idx & 127;
            uint4 v = *(const uint4*)&Wb[(size_t)(n0 + n) * KF + (c0 + c) * 8];
            *(uint4*)&Bs[(c * 128 + n) * 8] = v;
        }
        __syncthreads();

        const int kbeg = c0 * 8;
        const int kend = kbeg + nch * 8;

        // prefetch A for first kb of this half
        short8 af[4], afn[4];
        #pragma unroll
        for (int i = 0; i < 4; ++i)
            af[i] = *(const short8*)(Arow + (size_t)(i * 16) * KF + kbeg);

        for (int kb = kbeg; kb < kend; kb += 32) {
            // prefetch next kb's A-frags (clamped; dead loads on last iter are cheap)
            int kbn = (kb + 32 < kend) ? kb + 32 : kb;
            #pragma unroll
            for (int i = 0; i < 4; ++i)
                afn[i] = *(const short8*)(Arow + (size_t)(i * 16) * KF + kbn);

            // B-frags from LDS: n = j*16+ln, k = kb + lq*8 -> local chunk (kb-kbeg)/8 + lq
            const int cl = ((kb - kbeg) >> 3) + lq;
            short8 bf[8];
            #pragma unroll
            for (int j = 0; j < 8; ++j)
                bf[j] = *(const short8*)&Bs[(cl * 128 + j * 16 + ln) * 8];

            #pragma unroll
            for (int i = 0; i < 4; ++i)
                #pragma unroll
                for (int j = 0; j < 8; ++j)
                    acc[i][j] = __builtin_amdgcn_mfma_f32_16x16x32_bf16(af[i], bf[j], acc[i][j], 0, 0, 0);

            #pragma unroll
            for (int i = 0; i < 4; ++i) af[i] = afn[i];
        }
        __syncthreads();   // protect Bs before next half's restage
    }

    // epilogue: C/D col(n)=lane&15 side, row(m)=lq*4+reg (verified m89/m91 convention)
    #pragma unroll
    for (int j = 0; j < 8; ++j) {
        int n = n0 + j * 16 + ln;
        if (n >= 1000) continue;
        float bias = lb[n];
        #pragma unroll
        for (int i = 0; i < 4; ++i) {
            int mb = mbase + i * 16 + lq * 4;
            #pragma unroll
            for (int rr = 0; rr < 4; ++rr)
                out[(size_t)(mb + rr) * 1000 + n] = acc[i][j][rr] + bias;
        }
    }
}

extern "C" void kernel_launch(void* const* d_in, const int* in_sizes, int n_in,
                              void* d_out, int out_size, void* d_ws, size_t ws_size,
                              hipStream_t stream)
{
    const float* fm = (const float*)d_in[0];   // (32768,3,14,14)
    const float* cw = (const float*)d_in[1];   // (16,3,5,5)
    const float* cb = (const float*)d_in[2];   // (16,)
    const float* lw = (const float*)d_in[3];   // (1000,400)
    const float* lb = (const float*)d_in[4];   // (1000,)
    float* out = (float*)d_out;                // (32768,1000) fp32

    unsigned short* feat = (unsigned short*)d_ws;                        // [32768][416] bf16
    unsigned short* Wb   = (unsigned short*)d_ws + (size_t)BTOT * KF;    // [1024][416] bf16

    prep_w_kernel<<<208, 256, 0, stream>>>(lw, Wb);
    conv_pool_kernel<<<BTOT / NIMG, 256, 0, stream>>>(fm, cw, cb, feat);
    gemm_kernel<<<512, 512, 0, stream>>>(feat, Wb, lb, out);
}